// Round 8
// baseline (511.275 us; speedup 1.0000x reference)
//
#include <hip/hip_runtime.h>
#include <hip/hip_fp16.h>
#include <math.h>

#define N_ITERS 20

typedef short short8 __attribute__((ext_vector_type(8)));    // 8 bf16
typedef _Float16 half2v __attribute__((ext_vector_type(2)));
typedef float floatx4 __attribute__((ext_vector_type(4)));

__device__ __forceinline__ unsigned short f2bf(float f) {
    unsigned int u = __float_as_uint(f);
    u += 0x7FFFu + ((u >> 16) & 1u);   // RNE
    return (unsigned short)(u >> 16);
}

__device__ __forceinline__ float dot8(uint4 e, uint4 v, float s) {
#if __has_builtin(__builtin_amdgcn_fdot2)
    const half2v* ep = (const half2v*)&e;
    const half2v* vp = (const half2v*)&v;
    s = __builtin_amdgcn_fdot2(ep[0], vp[0], s, false);
    s = __builtin_amdgcn_fdot2(ep[1], vp[1], s, false);
    s = __builtin_amdgcn_fdot2(ep[2], vp[2], s, false);
    s = __builtin_amdgcn_fdot2(ep[3], vp[3], s, false);
#else
    const _Float16* ep = (const _Float16*)&e;
    const _Float16* vp = (const _Float16*)&v;
#pragma unroll
    for (int i = 0; i < 8; ++i) s += (float)ep[i] * (float)vp[i];
#endif
    return s;
}

// ---------------- prep ----------------
__global__ __launch_bounds__(256) void convert_x(const float* __restrict__ x,
                                                 unsigned short* __restrict__ xb) {
    const int i = (blockIdx.x * 256 + threadIdx.x) << 4;
    unsigned short tmp[16];
#pragma unroll
    for (int p = 0; p < 4; ++p) {
        float4 f = *(const float4*)&x[i + (p << 2)];
        tmp[p * 4 + 0] = f2bf(f.x); tmp[p * 4 + 1] = f2bf(f.y);
        tmp[p * 4 + 2] = f2bf(f.z); tmp[p * 4 + 3] = f2bf(f.w);
    }
    *(uint4*)&xb[i]     = *(const uint4*)&tmp[0];
    *(uint4*)&xb[i + 8] = *(const uint4*)&tmp[8];
}

__global__ __launch_bounds__(256) void transpose_all(
    const float* __restrict__ Wq, const float* __restrict__ Wk,
    const float* __restrict__ Wv, const float* __restrict__ Wo,
    unsigned short* __restrict__ wqT, unsigned short* __restrict__ wkT,
    unsigned short* __restrict__ wvT, unsigned short* __restrict__ woT)
{
    const int z = blockIdx.z;
    const float* S; unsigned short* D; int rows, cols;
    if (z == 0)      { S = Wq; D = wqT; rows = 1024; cols = 512; }
    else if (z == 1) { S = Wk; D = wkT; rows = 1024; cols = 512; }
    else if (z == 2) { S = Wv; D = wvT; rows = 1024; cols = 512; }
    else             { S = Wo; D = woT; rows = 512;  cols = 1024; }
    const int n0 = blockIdx.x << 5, k0 = blockIdx.y << 5;
    if (n0 >= cols || k0 >= rows) return;
    __shared__ float Tls[32][33];
    const int t = threadIdx.x;
    const int rl = t >> 5, cl = t & 31;
#pragma unroll
    for (int i = 0; i < 4; ++i)
        Tls[rl + (i << 3)][cl] = S[(size_t)(k0 + rl + (i << 3)) * cols + n0 + cl];
    __syncthreads();
#pragma unroll
    for (int i = 0; i < 4; ++i)
        D[(size_t)(n0 + rl + (i << 3)) * rows + k0 + cl] = f2bf(Tls[cl][rl + (i << 3)]);
}

// ---------------- QKV projection: 64x64-tile bf16 MFMA GEMM ----------------
__global__ __launch_bounds__(256) void qkv64(
    const unsigned short* __restrict__ xb,
    const unsigned short* __restrict__ wqT, const unsigned short* __restrict__ wkT,
    const unsigned short* __restrict__ wvT,
    const float* __restrict__ bq, const float* __restrict__ bk, const float* __restrict__ bv,
    unsigned short* __restrict__ qb, unsigned short* __restrict__ kb,
    unsigned short* __restrict__ vt)
{
    const int pz = blockIdx.z;
    const unsigned short* Bt = (pz == 0) ? wqT : (pz == 1) ? wkT : wvT;
    const float* bias = (pz == 0) ? bq : (pz == 1) ? bk : bv;
    __shared__ __align__(16) unsigned short Als[64 * 72];
    __shared__ __align__(16) unsigned short Bls[64 * 72];
    const int t = threadIdx.x;
    const int m0 = blockIdx.y << 6, n0 = blockIdx.x << 6;
    const int w = t >> 6, lane = t & 63, quad = lane >> 4, l16 = lane & 15;
    const int lrow = t >> 2, lk = (t & 3) << 4;
    floatx4 acc[4] = {};
    for (int k0 = 0; k0 < 1024; k0 += 64) {
        uint4 a0 = *(const uint4*)&xb[(size_t)(m0 + lrow) * 1024 + k0 + lk];
        uint4 a1 = *(const uint4*)&xb[(size_t)(m0 + lrow) * 1024 + k0 + lk + 8];
        uint4 b0 = *(const uint4*)&Bt[(size_t)(n0 + lrow) * 1024 + k0 + lk];
        uint4 b1 = *(const uint4*)&Bt[(size_t)(n0 + lrow) * 1024 + k0 + lk + 8];
        __syncthreads();
        *(uint4*)&Als[lrow * 72 + lk] = a0;
        *(uint4*)&Als[lrow * 72 + lk + 8] = a1;
        *(uint4*)&Bls[lrow * 72 + lk] = b0;
        *(uint4*)&Bls[lrow * 72 + lk + 8] = b1;
        __syncthreads();
        short8 af0 = *(const short8*)&Als[(w * 16 + l16) * 72 + quad * 8];
        short8 af1 = *(const short8*)&Als[(w * 16 + l16) * 72 + 32 + quad * 8];
#pragma unroll
        for (int nt = 0; nt < 4; ++nt) {
            short8 g0 = *(const short8*)&Bls[(nt * 16 + l16) * 72 + quad * 8];
            short8 g1 = *(const short8*)&Bls[(nt * 16 + l16) * 72 + 32 + quad * 8];
            acc[nt] = __builtin_amdgcn_mfma_f32_16x16x32_bf16(af0, g0, acc[nt], 0, 0, 0);
            acc[nt] = __builtin_amdgcn_mfma_f32_16x16x32_bf16(af1, g1, acc[nt], 0, 0, 0);
        }
    }
#pragma unroll
    for (int nt = 0; nt < 4; ++nt) {
        const int gn = n0 + nt * 16 + l16;
        const float bb = bias[gn];
        const int h = gn >> 6, d = gn & 63;
#pragma unroll
        for (int p = 0; p < 4; ++p) {
            const int gm = m0 + w * 16 + quad * 4 + p;
            const int batch = gm >> 10, l = gm & 1023;
            const int bhx = (batch << 3) + h;
            const float val = acc[nt][p] + bb;
            if (pz < 2) {
                unsigned short* dst = (pz == 0) ? qb : kb;
                dst[((size_t)((bhx << 10) + l) << 6) + d] = f2bf(val);
            } else {
                vt[((size_t)bhx << 16) + ((size_t)d << 10) + l] = f2bf(val);  // V^T [bh][d][l]
            }
        }
    }
}

// ---------------- E = exp(q @ k^T / 8) -> fp16 (r3-verified) ----------------
__global__ __launch_bounds__(256) void mfma_logits(
    const unsigned short* __restrict__ qb, const unsigned short* __restrict__ kb,
    __half* __restrict__ E)
{
    const int bh = blockIdx.z;
    const int m0 = blockIdx.y << 7, n0 = blockIdx.x << 7;
    __shared__ __align__(16) unsigned short Qls[128 * 72];
    __shared__ __align__(16) unsigned short Kls[128 * 72];
    const int t = threadIdx.x;
    const int w = t >> 6, lane = t & 63;
    const int quad = lane >> 4, l16 = lane & 15;
    const int wr = w >> 1, wc = w & 1;
    const size_t base = (size_t)bh << 10;
#pragma unroll
    for (int i = 0; i < 4; ++i) {
        int ch = t + (i << 8);
        int row = ch >> 3, ko = (ch & 7) << 3;
        *(uint4*)&Qls[row * 72 + ko] = *(const uint4*)&qb[(base + m0 + row) * 64 + ko];
        *(uint4*)&Kls[row * 72 + ko] = *(const uint4*)&kb[(base + n0 + row) * 64 + ko];
    }
    __syncthreads();
    floatx4 acc[4][4] = {};
#pragma unroll
    for (int kk = 0; kk < 64; kk += 32) {
        short8 af[4], bf[4];
#pragma unroll
        for (int i = 0; i < 4; ++i)
            af[i] = *(const short8*)&Qls[(wr * 64 + i * 16 + l16) * 72 + kk + quad * 8];
#pragma unroll
        for (int j = 0; j < 4; ++j)
            bf[j] = *(const short8*)&Kls[(wc * 64 + j * 16 + l16) * 72 + kk + quad * 8];
#pragma unroll
        for (int i = 0; i < 4; ++i)
#pragma unroll
            for (int j = 0; j < 4; ++j)
                acc[i][j] = __builtin_amdgcn_mfma_f32_16x16x32_bf16(af[i], bf[j], acc[i][j], 0, 0, 0);
    }
#pragma unroll
    for (int i = 0; i < 4; ++i)
#pragma unroll
    for (int p = 0; p < 4; ++p) {
        int gm = m0 + wr * 64 + i * 16 + quad * 4 + p;
#pragma unroll
        for (int j = 0; j < 4; ++j) {
            int gn = n0 + wc * 64 + j * 16 + l16;
            E[((size_t)bh << 20) + ((size_t)gm << 10) + gn] =
                __float2half(__expf(acc[i][j][p] * 0.125f));
        }
    }
}

// ---------------- one Sinkhorn iteration per launch (it = 1..20) ----------------
// Launch boundary IS the device barrier (CP-driven L2 flush/inv): plain cached
// loads/stores only -- no LLC atomics, no spinning (r4-r7 floor was ~16us/iter
// on any intra-kernel sync; launch relay costs ~1.5us + cached traffic).
// Block (bh,chunk) owns rows [chunk*64, chunk*64+64). part[parity][bh][slice][1024].
__global__ __launch_bounds__(512) void sink_pass(
    const __half* __restrict__ E, float* __restrict__ u,
    float* __restrict__ part, int it)
{
    __shared__ __align__(16) _Float16 vlh[1024];
    __shared__ float wacc[1024];   // bank-permuted: col c -> (c&7)*128 + (c>>3)
    const int t = threadIdx.x;
    const int w = t >> 6, lane = t & 63;
    const int bh = blockIdx.x >> 4, chunk = blockIdx.x & 15;
    const int m0 = chunk << 6;

    // merge v from previous launch's 16 slices (plain cached loads)
    if (it == 1) {
        vlh[t] = (_Float16)1.0f; vlh[t + 512] = (_Float16)1.0f;
    } else {
        const float* pb = part + ((size_t)(((it - 1) & 1) * 16 + bh) << 14);
        const int c0 = t << 1;
        float s0 = 0.0f, s1 = 0.0f;
#pragma unroll
        for (int sl = 0; sl < 16; ++sl) {
            float2 f = *(const float2*)(pb + (sl << 10) + c0);
            s0 += f.x; s1 += f.y;
        }
        vlh[c0]     = (_Float16)(1.0f / s0);
        vlh[c0 + 1] = (_Float16)(1.0f / s1);
    }
    wacc[t] = 0.0f; wacc[t + 512] = 0.0f;
    __syncthreads();

    const int r0 = w << 3;  // 8 rows per wave
    uint4 vh0 = *(const uint4*)(vlh + lane * 8);
    uint4 vh1 = *(const uint4*)(vlh + 512 + lane * 8);
    const __half* Eb = E + (((size_t)(bh << 10) + m0) << 10);
    float acc[16] = {};
#pragma unroll
    for (int hf = 0; hf < 2; ++hf) {
        uint4 e0[4], e1[4];
        float s[4];
#pragma unroll
        for (int rr = 0; rr < 4; ++rr) {
            const __half* erow = Eb + ((size_t)(r0 + hf * 4 + rr) << 10);
            e0[rr] = *(const uint4*)(erow + lane * 8);
            e1[rr] = *(const uint4*)(erow + 512 + lane * 8);
            float ss = 0.0f;
            ss = dot8(e0[rr], vh0, ss);
            ss = dot8(e1[rr], vh1, ss);
            s[rr] = ss;
        }
#pragma unroll
        for (int off = 32; off > 0; off >>= 1)
#pragma unroll
            for (int rr = 0; rr < 4; ++rr)
                s[rr] += __shfl_xor(s[rr], off);
#pragma unroll
        for (int rr = 0; rr < 4; ++rr) {
            const float ui = 1.0f / s[rr];
            if (lane == 0) u[(bh << 10) + m0 + r0 + hf * 4 + rr] = ui;
            const _Float16* ep0 = (const _Float16*)&e0[rr];
            const _Float16* ep1 = (const _Float16*)&e1[rr];
#pragma unroll
            for (int k = 0; k < 8; ++k) {
                acc[k]     += (float)ep0[k] * ui;
                acc[8 + k] += (float)ep1[k] * ui;
            }
        }
    }
#pragma unroll
    for (int k = 0; k < 8; ++k) {
        atomicAdd(&wacc[k * 128 + lane], acc[k]);
        atomicAdd(&wacc[k * 128 + 64 + lane], acc[8 + k]);
    }
    __syncthreads();
    // publish this block's slice (plain coalesced stores; next launch reads)
    float* slice = part + ((size_t)((it & 1) * 16 + bh) << 14) + (chunk << 10);
    const int c0 = t << 1;
    float2 pp;
    pp.x = wacc[(c0 & 7) * 128 + (c0 >> 3)];
    pp.y = wacc[((c0 + 1) & 7) * 128 + ((c0 + 1) >> 3)];
    *(float2*)(slice + c0) = pp;
}

// ---------------- out_pre = diag(u) * E * diag(v) @ V via bf16 MFMA ----------------
// v merged in-kernel from part[0] (it=20 parity). r3-verified MFMA structure.
__global__ __launch_bounds__(256) void attn_mfma(
    const __half* __restrict__ E, const float* __restrict__ u,
    const float* __restrict__ part, const unsigned short* __restrict__ vt,
    unsigned short* __restrict__ o_p)
{
    const int bh = blockIdx.y;
    const int m0 = blockIdx.x << 6;
    const int b = bh >> 3, h = bh & 7;
    __shared__ __align__(16) unsigned short Pls[64 * 72];
    __shared__ __align__(16) unsigned short Vls[64 * 72];
    __shared__ float vmerge[1024];
    const int t = threadIdx.x;
    const int w = t >> 6, lane = t & 63;
    const int quad = lane >> 4, l16 = lane & 15;
    // merge final v
#pragma unroll
    for (int p = 0; p < 4; ++p) {
        const int c = t + (p << 8);
        const float* pb = part + ((size_t)bh << 14) + c;
        float s = 0.0f;
#pragma unroll
        for (int sl = 0; sl < 16; ++sl) s += pb[sl << 10];
        vmerge[c] = 1.0f / s;
    }
    __syncthreads();
    floatx4 acc[4] = {};
    for (int j0 = 0; j0 < 1024; j0 += 64) {
        __syncthreads();
#pragma unroll
        for (int p = 0; p < 2; ++p) {
            int cidx = t + (p << 8);
            int row = cidx >> 3, c8 = (cidx & 7) << 3;
            uint4 hx = *(const uint4*)&E[(((size_t)(bh << 10) + m0 + row) << 10) + j0 + c8];
            const __half* hp = (const __half*)&hx;
            float ur = u[(bh << 10) + m0 + row];
            float4 v0 = *(const float4*)&vmerge[j0 + c8];
            float4 v1 = *(const float4*)&vmerge[j0 + c8 + 4];
            unsigned short pk[8];
            pk[0] = f2bf(__half2float(hp[0]) * ur * v0.x);
            pk[1] = f2bf(__half2float(hp[1]) * ur * v0.y);
            pk[2] = f2bf(__half2float(hp[2]) * ur * v0.z);
            pk[3] = f2bf(__half2float(hp[3]) * ur * v0.w);
            pk[4] = f2bf(__half2float(hp[4]) * ur * v1.x);
            pk[5] = f2bf(__half2float(hp[5]) * ur * v1.y);
            pk[6] = f2bf(__half2float(hp[6]) * ur * v1.z);
            pk[7] = f2bf(__half2float(hp[7]) * ur * v1.w);
            *(uint4*)&Pls[row * 72 + c8] = *(const uint4*)pk;
            *(uint4*)&Vls[row * 72 + c8] =
                *(const uint4*)&vt[((size_t)bh << 16) + ((size_t)row << 10) + j0 + c8];
        }
        __syncthreads();
#pragma unroll
        for (int kk = 0; kk < 64; kk += 32) {
            short8 af = *(const short8*)&Pls[(w * 16 + l16) * 72 + kk + quad * 8];
#pragma unroll
            for (int j = 0; j < 4; ++j) {
                short8 bfv = *(const short8*)&Vls[(j * 16 + l16) * 72 + kk + quad * 8];
                acc[j] = __builtin_amdgcn_mfma_f32_16x16x32_bf16(af, bfv, acc[j], 0, 0, 0);
            }
        }
    }
#pragma unroll
    for (int j = 0; j < 4; ++j)
#pragma unroll
    for (int p = 0; p < 4; ++p) {
        int l = m0 + w * 16 + quad * 4 + p;
        int d = (j << 4) + l16;
        o_p[((size_t)((b << 10) + l)) * 512 + (h << 6) + d] = f2bf(acc[j][p]);
    }
}

// ---------------- out = o_p(bf16 2048x512) @ Wo + bo : 64x64-tile MFMA ----------------
__global__ __launch_bounds__(256) void out64(
    const unsigned short* __restrict__ A, const unsigned short* __restrict__ BT,
    const float* __restrict__ bo, float* __restrict__ C)
{
    __shared__ __align__(16) unsigned short Als[64 * 72];
    __shared__ __align__(16) unsigned short Bls[64 * 72];
    const int t = threadIdx.x;
    const int m0 = blockIdx.y << 6, n0 = blockIdx.x << 6;
    const int w = t >> 6, lane = t & 63, quad = lane >> 4, l16 = lane & 15;
    const int lrow = t >> 2, lk = (t & 3) << 4;
    floatx4 acc[4] = {};
    for (int k0 = 0; k0 < 512; k0 += 64) {
        uint4 a0 = *(const uint4*)&A[(size_t)(m0 + lrow) * 512 + k0 + lk];
        uint4 a1 = *(const uint4*)&A[(size_t)(m0 + lrow) * 512 + k0 + lk + 8];
        uint4 b0 = *(const uint4*)&BT[(size_t)(n0 + lrow) * 512 + k0 + lk];
        uint4 b1 = *(const uint4*)&BT[(size_t)(n0 + lrow) * 512 + k0 + lk + 8];
        __syncthreads();
        *(uint4*)&Als[lrow * 72 + lk] = a0;
        *(uint4*)&Als[lrow * 72 + lk + 8] = a1;
        *(uint4*)&Bls[lrow * 72 + lk] = b0;
        *(uint4*)&Bls[lrow * 72 + lk + 8] = b1;
        __syncthreads();
        short8 af0 = *(const short8*)&Als[(w * 16 + l16) * 72 + quad * 8];
        short8 af1 = *(const short8*)&Als[(w * 16 + l16) * 72 + 32 + quad * 8];
#pragma unroll
        for (int nt = 0; nt < 4; ++nt) {
            short8 g0 = *(const short8*)&Bls[(nt * 16 + l16) * 72 + quad * 8];
            short8 g1 = *(const short8*)&Bls[(nt * 16 + l16) * 72 + 32 + quad * 8];
            acc[nt] = __builtin_amdgcn_mfma_f32_16x16x32_bf16(af0, g0, acc[nt], 0, 0, 0);
            acc[nt] = __builtin_amdgcn_mfma_f32_16x16x32_bf16(af1, g1, acc[nt], 0, 0, 0);
        }
    }
#pragma unroll
    for (int nt = 0; nt < 4; ++nt) {
        const int gn = n0 + nt * 16 + l16;
        const float bb = bo[gn];
#pragma unroll
        for (int p = 0; p < 4; ++p) {
            const int gm = m0 + w * 16 + quad * 4 + p;
            C[(size_t)gm * 1024 + gn] = acc[nt][p] + bb;
        }
    }
}

extern "C" void kernel_launch(void* const* d_in, const int* in_sizes, int n_in,
                              void* d_out, int out_size, void* d_ws, size_t ws_size,
                              hipStream_t stream)
{
    const float* x  = (const float*)d_in[0];
    const float* Wq = (const float*)d_in[1];
    const float* bq = (const float*)d_in[2];
    const float* Wk = (const float*)d_in[3];
    const float* bk = (const float*)d_in[4];
    const float* Wv = (const float*)d_in[5];
    const float* bv = (const float*)d_in[6];
    const float* Wo = (const float*)d_in[7];
    const float* bo = (const float*)d_in[8];
    float* out = (float*)d_out;

    char* W = (char*)d_ws;
    unsigned short* xb  = (unsigned short*)(W);                    // 4 MB
    unsigned short* wqT = (unsigned short*)(W + (4ll  << 20));     // 1 MB
    unsigned short* wkT = (unsigned short*)(W + (5ll  << 20));     // 1 MB
    unsigned short* wvT = (unsigned short*)(W + (6ll  << 20));     // 1 MB
    unsigned short* woT = (unsigned short*)(W + (7ll  << 20));     // 1 MB
    unsigned short* qb  = (unsigned short*)(W + (8ll  << 20));     // 2 MB
    unsigned short* kb  = (unsigned short*)(W + (10ll << 20));     // 2 MB
    unsigned short* vt  = (unsigned short*)(W + (12ll << 20));     // 2 MB
    unsigned short* o_p = (unsigned short*)(W + (14ll << 20));     // 2 MB
    __half* E           = (__half*)(W + (16ll << 20));             // 32 MB
    float* u            = (float*)(W + (48ll << 20));              // 64 KB
    float* part         = (float*)(W + (49ll << 20));              // 2 MB [2][16][16][1024]

    convert_x<<<512, 256, 0, stream>>>(x, xb);
    transpose_all<<<dim3(32, 32, 4), 256, 0, stream>>>(Wq, Wk, Wv, Wo, wqT, wkT, wvT, woT);
    qkv64<<<dim3(8, 32, 3), 256, 0, stream>>>(xb, wqT, wkT, wvT, bq, bk, bv, qb, kb, vt);
    mfma_logits<<<dim3(8, 8, 16), 256, 0, stream>>>(qb, kb, E);
    for (int it = 1; it <= N_ITERS; ++it)
        sink_pass<<<256, 512, 0, stream>>>(E, u, part, it);
    attn_mfma<<<dim3(16, 16), 256, 0, stream>>>(E, u, part, vt, o_p);  // parity 20&1=0
    out64<<<dim3(16, 32), 256, 0, stream>>>(o_p, woT, bo, out);
}